// Round 2
// baseline (271.372 us; speedup 1.0000x reference)
//
#include <hip/hip_runtime.h>

#define F_IN 256
#define F_OUT 64
#define BSH 7             // bin width 128 nodes
#define BINW 128
#define NBINS_CAP 512     // LDS histogram capacity (N <= 65536)
#define EPB 4096          // phase-1 edges per block (8 per thread, in regs)
#define CSTRIDE 16        // cursor padded to one 64B line per bin (R9 lesson)

typedef __attribute__((ext_vector_type(8))) short short8;
typedef __attribute__((ext_vector_type(4))) float f32x4;

// ---------------------------------------------------------------------------
// bf16 helpers (RNE).
// ---------------------------------------------------------------------------
__device__ inline unsigned short f2bf_rne(float f) {
    unsigned u = __float_as_uint(f);
    return (unsigned short)((u + 0x7fffu + ((u >> 16) & 1u)) >> 16);
}
__device__ inline float bf_lo(unsigned u) { return __uint_as_float(u << 16); }
__device__ inline float bf_hi(unsigned u) { return __uint_as_float(u & 0xFFFF0000u); }
__device__ inline short8 pack_rne(float4 a, float4 b) {
    union { unsigned u[4]; short8 s; } r;
    r.u[0] = f2bf_rne(a.x) | ((unsigned)f2bf_rne(a.y) << 16);
    r.u[1] = f2bf_rne(a.z) | ((unsigned)f2bf_rne(a.w) << 16);
    r.u[2] = f2bf_rne(b.x) | ((unsigned)f2bf_rne(b.y) << 16);
    r.u[3] = f2bf_rne(b.z) | ((unsigned)f2bf_rne(b.w) << 16);
    return r.s;
}

// ---------------------------------------------------------------------------
// Manual grid barrier (single-use counter per barrier instance, zeroed by the
// host memset). Plain-kernel replacement for cg::grid_group::sync() — R1's
// hipLaunchCooperativeKernel appears incompatible with the harness's graph
// capture (container failed twice). Safe iff all blocks co-resident, which the
// host guarantees: grid = min(nbins, occ*CU), occ >= 2 by launch_bounds+LDS.
// ---------------------------------------------------------------------------
__device__ inline void gbar(int* ctr, int gsz) {
    __syncthreads();
    if (threadIdx.x == 0) {
        __threadfence();  // device-scope release of prior writes
        __hip_atomic_fetch_add(ctr, 1, __ATOMIC_ACQ_REL, __HIP_MEMORY_SCOPE_AGENT);
        while (__hip_atomic_load(ctr, __ATOMIC_ACQUIRE, __HIP_MEMORY_SCOPE_AGENT) < gsz)
            __builtin_amdgcn_s_sleep(1);
        __threadfence();  // device-scope acquire side, belt-and-braces
    }
    __syncthreads();
}

// ---------------------------------------------------------------------------
// Fused kernel: [P1 bin edges] -> bar -> [P2 scan+scatter CSR + dinv] -> bar
// -> [P3 gemm g = dinv*(x@W) via bf16 MFMA]. Collapses 3 dispatches into 1.
// Phase bodies are the proven R10 code re-indexed for 512 threads; P1 stages
// 8 edges/thread so each cursor line sees 196 atomic rounds instead of 782.
// ---------------------------------------------------------------------------
__global__ __launch_bounds__(512, 4) void gcn_fused(
    const float* __restrict__ x, const int* __restrict__ adj,
    const float* __restrict__ W, float* __restrict__ dinv,
    int* __restrict__ cursor, int* __restrict__ bar, int* __restrict__ rowOff,
    unsigned short* __restrict__ csr, unsigned* __restrict__ staging,
    unsigned* __restrict__ gu, int N, int E, int nbins, int maxBin) {
    __shared__ union {
        struct { int cnt[NBINS_CAP]; int base[NBINS_CAP]; } p1;
        struct { int degL[BINW]; int cur[BINW]; int wsum[2]; int baseSh; } p2;
        unsigned Wf[(F_IN / 8) * F_OUT * 4];  // 32 KB
    } sh;

    const int tid = threadIdx.x;
    const int bx = blockIdx.x;
    const int gsz = gridDim.x;

    // ---- P1: bin edges by dst>>BSH into per-bin staging ----
    const int nbat = (E + EPB - 1) / EPB;
    for (int bat = bx; bat < nbat; bat += gsz) {
        for (int i = tid; i < NBINS_CAP; i += 512) sh.p1.cnt[i] = 0;
        __syncthreads();
        int S[8], D[8], sl[8];
        const int e = bat * EPB + tid * 8;
        int nv = 0;
        if (e + 8 <= E && (E & 7) == 0) {
            *(int4*)&S[0] = *(const int4*)&adj[e];
            *(int4*)&S[4] = *(const int4*)&adj[e + 4];
            *(int4*)&D[0] = *(const int4*)&adj[E + e];
            *(int4*)&D[4] = *(const int4*)&adj[E + e + 4];
            nv = 8;
        } else if (e < E) {
            for (int k = 0; k < 8 && e + k < E; k++) {
                S[k] = adj[e + k];
                D[k] = adj[E + e + k];
                nv++;
            }
        }
#pragma unroll
        for (int j = 0; j < 8; j++)
            if (j < nv) sl[j] = atomicAdd(&sh.p1.cnt[D[j] >> BSH], 1);
        __syncthreads();
        for (int i = tid; i < nbins; i += 512) {
            int cv = sh.p1.cnt[i];
            sh.p1.base[i] = cv ? atomicAdd(&cursor[i * CSTRIDE], cv) : 0;
        }
        __syncthreads();
#pragma unroll
        for (int j = 0; j < 8; j++) {
            if (j < nv) {
                int bb = D[j] >> BSH;
                int pos = sh.p1.base[bb] + sl[j];
                if (pos < maxBin)
                    staging[(size_t)bb * maxBin + pos] =
                        (unsigned)S[j] | ((unsigned)(D[j] & (BINW - 1)) << 16);
            }
        }
        __syncthreads();
    }
    gbar(&bar[0], gsz);

    // ---- P2: per-bin scan + scatter (one 128-node bin per iteration) ----
    for (int b = bx; b < nbins; b += gsz) {
        const int nb0 = b << BSH;
        const int segCnt = min(cursor[b * CSTRIDE], maxBin);
        const unsigned* seg = staging + (size_t)b * maxBin;

        if (tid < 64) {  // base = staged edges in bins before this one
            int v = 0;
            for (int j = tid; j < b; j += 64) v += min(cursor[j * CSTRIDE], maxBin);
            for (int d = 1; d < 64; d <<= 1) v += __shfl_xor(v, d, 64);
            if (tid == 0) sh.p2.baseSh = v;
        }
        if (tid < BINW) sh.p2.degL[tid] = 0;
        __syncthreads();
        const int base = sh.p2.baseSh;

        for (int i = tid; i < segCnt; i += 512) atomicAdd(&sh.p2.degL[seg[i] >> 16], 1);
        __syncthreads();

        int incl = 0, v = 0;
        if (tid < BINW) {  // 2-wave exclusive scan of degL[128]
            const int lane = tid & 63;
            v = sh.p2.degL[tid];
            incl = v;
            for (int d = 1; d < 64; d <<= 1) {
                int t = __shfl_up(incl, d, 64);
                if (lane >= d) incl += t;
            }
            if (lane == 63) sh.p2.wsum[tid >> 6] = incl;
        }
        __syncthreads();
        if (tid < BINW) {
            int ex = incl - v + ((tid >= 64) ? sh.p2.wsum[0] : 0);
            sh.p2.cur[tid] = ex;
            int node = nb0 + tid;
            if (node < N) {
                rowOff[node] = base + ex;
                dinv[node] = rsqrtf((float)v + 1.0f);
            }
        }
        if (b == nbins - 1 && tid == 0) rowOff[N] = base + segCnt;
        __syncthreads();

        for (int i = tid; i < segCnt; i += 512) {
            unsigned e2 = seg[i];
            int pos = atomicAdd(&sh.p2.cur[e2 >> 16], 1);
            csr[base + pos] = (unsigned short)(e2 & 0xFFFFu);
        }
        __syncthreads();  // protect degL re-zero on next bin iteration
    }
    gbar(&bar[1], gsz);

    // ---- P3: g(bf16) = dinv[n] * (x @ W) via bf16 MFMA ----
    for (int p = tid; p < (F_IN / 2) * F_OUT; p += 512) {
        int kp = p >> 6;
        int n = p & 63;
        int k = kp * 2;
        unsigned lo = f2bf_rne(W[k * F_OUT + n]);
        unsigned hi = f2bf_rne(W[(k + 1) * F_OUT + n]);
        sh.Wf[((k >> 3) * 64 + n) * 4 + ((k & 7) >> 1)] = lo | (hi << 16);
    }
    __syncthreads();

    const int wave = tid >> 6;
    const int lane = tid & 63;
    const int q = lane >> 4;
    const int c = lane & 15;
    const int ntiles = (N + 127) >> 7;
    for (int tile = bx; tile < ntiles; tile += gsz) {
        const int n0 = tile * 128 + wave * 16;
        const int r = min(n0 + c, N - 1);
        const float* p0 = x + (size_t)r * F_IN + q * 8;

        f32x4 acc[4] = {};
#pragma unroll
        for (int s = 0; s < 8; s++) {
            float4 a0 = *(const float4*)(p0 + s * 32);
            float4 a1 = *(const float4*)(p0 + s * 32 + 4);
            short8 ah = pack_rne(a0, a1);
#pragma unroll
            for (int t = 0; t < 4; t++) {
                short8 bh = *(const short8*)&sh.Wf[((s * 4 + q) * 64 + t * 16 + c) * 4];
                acc[t] = __builtin_amdgcn_mfma_f32_16x16x32_bf16(ah, bh, acc[t], 0, 0, 0);
            }
        }
        // D layout: col = t*16+c (feature), row = q*4+rr (node).
#pragma unroll
        for (int rr = 0; rr < 4; rr++) {
            int node = n0 + q * 4 + rr;
            float dv = dinv[min(node, N - 1)];
#pragma unroll
            for (int t = 0; t < 4; t++) {
                float vv = acc[t][rr] * dv;
                float o = __shfl_xor(vv, 1, 64);
                if (node < N && !(lane & 1)) {
                    unsigned pk = (unsigned)f2bf_rne(vv) | ((unsigned)f2bf_rne(o) << 16);
                    gu[(size_t)node * 32 + t * 8 + (c >> 1)] = pk;
                }
            }
        }
    }
}

// ---------------------------------------------------------------------------
// K4: gather + fused epilogue (unchanged — kept separate for full occupancy;
// 12500 blocks of latency-hiding TLP that a co-resident grid can't give).
// ---------------------------------------------------------------------------
__global__ __launch_bounds__(256) void gather_epilogue(const unsigned short* __restrict__ csr,
                                                       const int* __restrict__ rowOff,
                                                       const float* __restrict__ dinv,
                                                       const unsigned* __restrict__ g32,
                                                       const float* __restrict__ bias,
                                                       float* __restrict__ out, int N) {
    int n = blockIdx.x * 4 + (threadIdx.x >> 6);
    if (n >= N) return;
    const int lane = threadIdx.x & 63;
    const int grp = lane >> 3;
    const int h = lane & 7;
    const int start = rowOff[n], end = rowOff[n + 1];
    const uint4* g4 = (const uint4*)g32;

    float a0[8] = {}, a1[8] = {};
    int i = start + grp;
    for (; i + 8 < end; i += 16) {
        int s0 = csr[i], s1 = csr[i + 8];
        uint4 u0 = g4[(size_t)s0 * 8 + h];
        uint4 u1 = g4[(size_t)s1 * 8 + h];
        a0[0] += bf_lo(u0.x); a0[1] += bf_hi(u0.x);
        a0[2] += bf_lo(u0.y); a0[3] += bf_hi(u0.y);
        a0[4] += bf_lo(u0.z); a0[5] += bf_hi(u0.z);
        a0[6] += bf_lo(u0.w); a0[7] += bf_hi(u0.w);
        a1[0] += bf_lo(u1.x); a1[1] += bf_hi(u1.x);
        a1[2] += bf_lo(u1.y); a1[3] += bf_hi(u1.y);
        a1[4] += bf_lo(u1.z); a1[5] += bf_hi(u1.z);
        a1[6] += bf_lo(u1.w); a1[7] += bf_hi(u1.w);
    }
    if (i < end) {
        int s0 = csr[i];
        uint4 u0 = g4[(size_t)s0 * 8 + h];
        a0[0] += bf_lo(u0.x); a0[1] += bf_hi(u0.x);
        a0[2] += bf_lo(u0.y); a0[3] += bf_hi(u0.y);
        a0[4] += bf_lo(u0.z); a0[5] += bf_hi(u0.z);
        a0[6] += bf_lo(u0.w); a0[7] += bf_hi(u0.w);
    }
    float acc[8];
#pragma unroll
    for (int k = 0; k < 8; k++) acc[k] = a0[k] + a1[k];
#pragma unroll
    for (int m = 8; m < 64; m <<= 1) {
#pragma unroll
        for (int k = 0; k < 8; k++) acc[k] += __shfl_xor(acc[k], m, 64);
    }
    if (grp == 0) {
        uint4 us = g4[(size_t)n * 8 + h];  // self loop
        float dv = dinv[n];
        float s0 = bf_lo(us.x), s1 = bf_hi(us.x), s2 = bf_lo(us.y), s3 = bf_hi(us.y);
        float s4 = bf_lo(us.z), s5 = bf_hi(us.z), s6 = bf_lo(us.w), s7 = bf_hi(us.w);
        float4 b0 = *(const float4*)&bias[h * 8];
        float4 b1 = *(const float4*)&bias[h * 8 + 4];
        float4 r0, r1;
        r0.x = fmaxf(fmaf(dv, acc[0] + s0, b0.x), 0.0f);
        r0.y = fmaxf(fmaf(dv, acc[1] + s1, b0.y), 0.0f);
        r0.z = fmaxf(fmaf(dv, acc[2] + s2, b0.z), 0.0f);
        r0.w = fmaxf(fmaf(dv, acc[3] + s3, b0.w), 0.0f);
        r1.x = fmaxf(fmaf(dv, acc[4] + s4, b1.x), 0.0f);
        r1.y = fmaxf(fmaf(dv, acc[5] + s5, b1.y), 0.0f);
        r1.z = fmaxf(fmaf(dv, acc[6] + s6, b1.z), 0.0f);
        r1.w = fmaxf(fmaf(dv, acc[7] + s7, b1.w), 0.0f);
        *(float4*)&out[(size_t)n * F_OUT + h * 8] = r0;
        *(float4*)&out[(size_t)n * F_OUT + h * 8 + 4] = r1;
    }
}

extern "C" void kernel_launch(void* const* d_in, const int* in_sizes, int n_in,
                              void* d_out, int out_size, void* d_ws, size_t ws_size,
                              hipStream_t stream) {
    const float* x = (const float*)d_in[0];
    const int* adj = (const int*)d_in[1];
    const float* W = (const float*)d_in[2];
    const float* b = (const float*)d_in[3];
    float* out = (float*)d_out;

    int N = in_sizes[0] / F_IN;  // 50000 (u32/u16 packing assumes N <= 65536)
    int E = in_sizes[1] / 2;     // 800000
    int nbins = (N + BINW - 1) >> BSH;             // 391 (<= NBINS_CAP)
    const int avg = (E + nbins - 1) / nbins;       // ~2047
    int maxBin = ((avg + (avg >> 2)) + 63) & ~63;  // 2560, ~11 sd headroom

    // ws: dinv(N) | cursor(nbins*64B, padded)+bar(4) | rowOff(N+1) |
    //     csr(E u16) | staging(nbins*maxBin u32) | g16(N*32 u32)
    char* ws = (char*)d_ws;
    size_t segDinv = (((size_t)N * 4) + 255) & ~(size_t)255;
    size_t segCur = (((size_t)nbins * CSTRIDE * 4 + 64) + 255) & ~(size_t)255;
    size_t segRow = (((size_t)(N + 1) * 4) + 255) & ~(size_t)255;
    size_t segCsr = (((size_t)E * 2) + 255) & ~(size_t)255;
    size_t segStg = (((size_t)nbins * maxBin * 4) + 255) & ~(size_t)255;
    float* dinv = (float*)ws;
    int* cursor = (int*)(ws + segDinv);
    int* bar = cursor + nbins * CSTRIDE;  // inside zeroed cursor segment
    int* rowOff = (int*)(ws + segDinv + segCur);
    unsigned short* csr = (unsigned short*)(ws + segDinv + segCur + segRow);
    unsigned* staging = (unsigned*)(ws + segDinv + segCur + segRow + segCsr);
    unsigned* g16 = (unsigned*)(ws + segDinv + segCur + segRow + segCsr + segStg);

    hipMemsetAsync(cursor, 0, segCur, stream);  // zeroes cursors + barriers

    // Grid size: guaranteed co-residency (cached). Every phase is
    // grid-stride so any grid <= capacity is correct.
    static int s_grid = 0;
    if (s_grid == 0) {
        int occ = 0, dev = 0, cu = 0;
        hipOccupancyMaxActiveBlocksPerMultiprocessor(&occ, gcn_fused, 512, 0);
        hipGetDevice(&dev);
        hipDeviceGetAttribute(&cu, hipDeviceAttributeMultiprocessorCount, dev);
        if (occ < 1) occ = 1;
        if (cu < 1) cu = 256;
        long g = (long)occ * cu;
        s_grid = (int)(g < nbins ? g : nbins);  // 391 covers every phase width
    }

    gcn_fused<<<s_grid, 512, 0, stream>>>(x, adj, W, dinv, cursor, bar, rowOff,
                                          csr, staging, g16, N, E, nbins, maxBin);
    gather_epilogue<<<(N + 3) / 4, 256, 0, stream>>>(csr, rowOff, dinv, g16, b, out, N);
}

// Round 3
// 227.777 us; speedup vs baseline: 1.1914x; 1.1914x over previous
//
#include <hip/hip_runtime.h>

#define F_IN 256
#define F_OUT 64
#define BSH 7             // bin width 128 nodes
#define BINW 128
#define NBINS_CAP 512     // LDS histogram capacity (N <= 65536)
#define EPB 2048          // phase-1 edges per block (4 per thread, in regs)
#define CSTRIDE 16        // cursor padded to one 64B line per bin (R9 lesson)

typedef __attribute__((ext_vector_type(8))) short short8;
typedef __attribute__((ext_vector_type(4))) float f32x4;

// ---------------------------------------------------------------------------
// bf16 helpers (RNE).
// ---------------------------------------------------------------------------
__device__ inline unsigned short f2bf_rne(float f) {
    unsigned u = __float_as_uint(f);
    return (unsigned short)((u + 0x7fffu + ((u >> 16) & 1u)) >> 16);
}
__device__ inline float bf_lo(unsigned u) { return __uint_as_float(u << 16); }
__device__ inline float bf_hi(unsigned u) { return __uint_as_float(u & 0xFFFF0000u); }
__device__ inline short8 pack_rne(float4 a, float4 b) {
    union { unsigned u[4]; short8 s; } r;
    r.u[0] = f2bf_rne(a.x) | ((unsigned)f2bf_rne(a.y) << 16);
    r.u[1] = f2bf_rne(a.z) | ((unsigned)f2bf_rne(a.w) << 16);
    r.u[2] = f2bf_rne(b.x) | ((unsigned)f2bf_rne(b.y) << 16);
    r.u[3] = f2bf_rne(b.z) | ((unsigned)f2bf_rne(b.w) << 16);
    return r.s;
}

// ---------------------------------------------------------------------------
// Manual grid barrier, R12 fix. R11's version spun on an ACQUIRE agent load:
// on gfx950 every agent-acquire emits an L2 invalidate (per-XCD L2s are not
// coherent; coherence point is L3), so 391 spinners thrashed all 8 XCDs' L2s
// ~1e6 times -> VALUBusy 1.8%, 239us. Protocol now: one RELEASE fetch_add at
// arrival (single L2 writeback -- needed anyway for cross-XCD visibility),
// RELAXED spin loads (sc1 read from coherence point, NO invalidate), one
// acquire fence on exit. Cache maintenance per barrier: 391 wb + 391 inv.
// Safe iff all blocks co-resident (host guarantees grid <= occ*CU).
// ---------------------------------------------------------------------------
__device__ inline void gbar(int* ctr, int gsz) {
    __syncthreads();
    if (threadIdx.x == 0) {
        __hip_atomic_fetch_add(ctr, 1, __ATOMIC_RELEASE, __HIP_MEMORY_SCOPE_AGENT);
        while (__hip_atomic_load(ctr, __ATOMIC_RELAXED, __HIP_MEMORY_SCOPE_AGENT) < gsz)
            __builtin_amdgcn_s_sleep(8);
        __builtin_amdgcn_fence(__ATOMIC_ACQUIRE, "agent");
    }
    __syncthreads();
}

// ---------------------------------------------------------------------------
// Fused kernel: [P1 bin edges] -> bar -> [P2 scan+scatter CSR + dinv] -> bar
// -> [P3 gemm g = dinv*(x@W) via bf16 MFMA]. EPB=2048 so all 391 blocks work
// in P1 (R11's 4096 left half the grid idle).
// ---------------------------------------------------------------------------
__global__ __launch_bounds__(512, 4) void gcn_fused(
    const float* __restrict__ x, const int* __restrict__ adj,
    const float* __restrict__ W, float* __restrict__ dinv,
    int* __restrict__ cursor, int* __restrict__ bar, int* __restrict__ rowOff,
    unsigned short* __restrict__ csr, unsigned* __restrict__ staging,
    unsigned* __restrict__ gu, int N, int E, int nbins, int maxBin) {
    __shared__ union {
        struct { int cnt[NBINS_CAP]; int base[NBINS_CAP]; } p1;
        struct { int degL[BINW]; int cur[BINW]; int wsum[2]; int baseSh; } p2;
        unsigned Wf[(F_IN / 8) * F_OUT * 4];  // 32 KB
    } sh;

    const int tid = threadIdx.x;
    const int bx = blockIdx.x;
    const int gsz = gridDim.x;

    // ---- P1: bin edges by dst>>BSH into per-bin staging ----
    const int nbat = (E + EPB - 1) / EPB;
    for (int bat = bx; bat < nbat; bat += gsz) {
        for (int i = tid; i < NBINS_CAP; i += 512) sh.p1.cnt[i] = 0;
        __syncthreads();
        int S[4], D[4], sl[4];
        const int e = bat * EPB + tid * 4;
        int nv = 0;
        if (e + 4 <= E && (E & 3) == 0) {
            *(int4*)&S[0] = *(const int4*)&adj[e];
            *(int4*)&D[0] = *(const int4*)&adj[E + e];
            nv = 4;
        } else if (e < E) {
            for (int k = 0; k < 4 && e + k < E; k++) {
                S[k] = adj[e + k];
                D[k] = adj[E + e + k];
                nv++;
            }
        }
#pragma unroll
        for (int j = 0; j < 4; j++)
            if (j < nv) sl[j] = atomicAdd(&sh.p1.cnt[D[j] >> BSH], 1);
        __syncthreads();
        for (int i = tid; i < nbins; i += 512) {
            int cv = sh.p1.cnt[i];
            sh.p1.base[i] = cv ? atomicAdd(&cursor[i * CSTRIDE], cv) : 0;
        }
        __syncthreads();
#pragma unroll
        for (int j = 0; j < 4; j++) {
            if (j < nv) {
                int bb = D[j] >> BSH;
                int pos = sh.p1.base[bb] + sl[j];
                if (pos < maxBin)
                    staging[(size_t)bb * maxBin + pos] =
                        (unsigned)S[j] | ((unsigned)(D[j] & (BINW - 1)) << 16);
            }
        }
        __syncthreads();
    }
    gbar(&bar[0], gsz);

    // ---- P2: per-bin scan + scatter (one 128-node bin per iteration) ----
    for (int b = bx; b < nbins; b += gsz) {
        const int nb0 = b << BSH;
        const int segCnt = min(cursor[b * CSTRIDE], maxBin);
        const unsigned* seg = staging + (size_t)b * maxBin;

        if (tid < 64) {  // base = staged edges in bins before this one
            int v = 0;
            for (int j = tid; j < b; j += 64) v += min(cursor[j * CSTRIDE], maxBin);
            for (int d = 1; d < 64; d <<= 1) v += __shfl_xor(v, d, 64);
            if (tid == 0) sh.p2.baseSh = v;
        }
        if (tid < BINW) sh.p2.degL[tid] = 0;
        __syncthreads();
        const int base = sh.p2.baseSh;

        for (int i = tid; i < segCnt; i += 512) atomicAdd(&sh.p2.degL[seg[i] >> 16], 1);
        __syncthreads();

        int incl = 0, v = 0;
        if (tid < BINW) {  // 2-wave exclusive scan of degL[128]
            const int lane = tid & 63;
            v = sh.p2.degL[tid];
            incl = v;
            for (int d = 1; d < 64; d <<= 1) {
                int t = __shfl_up(incl, d, 64);
                if (lane >= d) incl += t;
            }
            if (lane == 63) sh.p2.wsum[tid >> 6] = incl;
        }
        __syncthreads();
        if (tid < BINW) {
            int ex = incl - v + ((tid >= 64) ? sh.p2.wsum[0] : 0);
            sh.p2.cur[tid] = ex;
            int node = nb0 + tid;
            if (node < N) {
                rowOff[node] = base + ex;
                dinv[node] = rsqrtf((float)v + 1.0f);
            }
        }
        if (b == nbins - 1 && tid == 0) rowOff[N] = base + segCnt;
        __syncthreads();

        for (int i = tid; i < segCnt; i += 512) {
            unsigned e2 = seg[i];
            int pos = atomicAdd(&sh.p2.cur[e2 >> 16], 1);
            csr[base + pos] = (unsigned short)(e2 & 0xFFFFu);
        }
        __syncthreads();  // protect degL re-zero on next bin iteration
    }
    gbar(&bar[1], gsz);

    // ---- P3: g(bf16) = dinv[n] * (x @ W) via bf16 MFMA ----
    for (int p = tid; p < (F_IN / 2) * F_OUT; p += 512) {
        int kp = p >> 6;
        int n = p & 63;
        int k = kp * 2;
        unsigned lo = f2bf_rne(W[k * F_OUT + n]);
        unsigned hi = f2bf_rne(W[(k + 1) * F_OUT + n]);
        sh.Wf[((k >> 3) * 64 + n) * 4 + ((k & 7) >> 1)] = lo | (hi << 16);
    }
    __syncthreads();

    const int wave = tid >> 6;
    const int lane = tid & 63;
    const int q = lane >> 4;
    const int c = lane & 15;
    const int ntiles = (N + 127) >> 7;
    for (int tile = bx; tile < ntiles; tile += gsz) {
        const int n0 = tile * 128 + wave * 16;
        const int r = min(n0 + c, N - 1);
        const float* p0 = x + (size_t)r * F_IN + q * 8;

        f32x4 acc[4] = {};
#pragma unroll
        for (int s = 0; s < 8; s++) {
            float4 a0 = *(const float4*)(p0 + s * 32);
            float4 a1 = *(const float4*)(p0 + s * 32 + 4);
            short8 ah = pack_rne(a0, a1);
#pragma unroll
            for (int t = 0; t < 4; t++) {
                short8 bh = *(const short8*)&sh.Wf[((s * 4 + q) * 64 + t * 16 + c) * 4];
                acc[t] = __builtin_amdgcn_mfma_f32_16x16x32_bf16(ah, bh, acc[t], 0, 0, 0);
            }
        }
        // D layout: col = t*16+c (feature), row = q*4+rr (node).
#pragma unroll
        for (int rr = 0; rr < 4; rr++) {
            int node = n0 + q * 4 + rr;
            float dv = dinv[min(node, N - 1)];
#pragma unroll
            for (int t = 0; t < 4; t++) {
                float vv = acc[t][rr] * dv;
                float o = __shfl_xor(vv, 1, 64);
                if (node < N && !(lane & 1)) {
                    unsigned pk = (unsigned)f2bf_rne(vv) | ((unsigned)f2bf_rne(o) << 16);
                    gu[(size_t)node * 32 + t * 8 + (c >> 1)] = pk;
                }
            }
        }
    }
}

// ---------------------------------------------------------------------------
// K4: gather + fused epilogue (unchanged — kept separate for full occupancy;
// 12500 blocks of latency-hiding TLP that a co-resident grid can't give).
// ---------------------------------------------------------------------------
__global__ __launch_bounds__(256) void gather_epilogue(const unsigned short* __restrict__ csr,
                                                       const int* __restrict__ rowOff,
                                                       const float* __restrict__ dinv,
                                                       const unsigned* __restrict__ g32,
                                                       const float* __restrict__ bias,
                                                       float* __restrict__ out, int N) {
    int n = blockIdx.x * 4 + (threadIdx.x >> 6);
    if (n >= N) return;
    const int lane = threadIdx.x & 63;
    const int grp = lane >> 3;
    const int h = lane & 7;
    const int start = rowOff[n], end = rowOff[n + 1];
    const uint4* g4 = (const uint4*)g32;

    float a0[8] = {}, a1[8] = {};
    int i = start + grp;
    for (; i + 8 < end; i += 16) {
        int s0 = csr[i], s1 = csr[i + 8];
        uint4 u0 = g4[(size_t)s0 * 8 + h];
        uint4 u1 = g4[(size_t)s1 * 8 + h];
        a0[0] += bf_lo(u0.x); a0[1] += bf_hi(u0.x);
        a0[2] += bf_lo(u0.y); a0[3] += bf_hi(u0.y);
        a0[4] += bf_lo(u0.z); a0[5] += bf_hi(u0.z);
        a0[6] += bf_lo(u0.w); a0[7] += bf_hi(u0.w);
        a1[0] += bf_lo(u1.x); a1[1] += bf_hi(u1.x);
        a1[2] += bf_lo(u1.y); a1[3] += bf_hi(u1.y);
        a1[4] += bf_lo(u1.z); a1[5] += bf_hi(u1.z);
        a1[6] += bf_lo(u1.w); a1[7] += bf_hi(u1.w);
    }
    if (i < end) {
        int s0 = csr[i];
        uint4 u0 = g4[(size_t)s0 * 8 + h];
        a0[0] += bf_lo(u0.x); a0[1] += bf_hi(u0.x);
        a0[2] += bf_lo(u0.y); a0[3] += bf_hi(u0.y);
        a0[4] += bf_lo(u0.z); a0[5] += bf_hi(u0.z);
        a0[6] += bf_lo(u0.w); a0[7] += bf_hi(u0.w);
    }
    float acc[8];
#pragma unroll
    for (int k = 0; k < 8; k++) acc[k] = a0[k] + a1[k];
#pragma unroll
    for (int m = 8; m < 64; m <<= 1) {
#pragma unroll
        for (int k = 0; k < 8; k++) acc[k] += __shfl_xor(acc[k], m, 64);
    }
    if (grp == 0) {
        uint4 us = g4[(size_t)n * 8 + h];  // self loop
        float dv = dinv[n];
        float s0 = bf_lo(us.x), s1 = bf_hi(us.x), s2 = bf_lo(us.y), s3 = bf_hi(us.y);
        float s4 = bf_lo(us.z), s5 = bf_hi(us.z), s6 = bf_lo(us.w), s7 = bf_hi(us.w);
        float4 b0 = *(const float4*)&bias[h * 8];
        float4 b1 = *(const float4*)&bias[h * 8 + 4];
        float4 r0, r1;
        r0.x = fmaxf(fmaf(dv, acc[0] + s0, b0.x), 0.0f);
        r0.y = fmaxf(fmaf(dv, acc[1] + s1, b0.y), 0.0f);
        r0.z = fmaxf(fmaf(dv, acc[2] + s2, b0.z), 0.0f);
        r0.w = fmaxf(fmaf(dv, acc[3] + s3, b0.w), 0.0f);
        r1.x = fmaxf(fmaf(dv, acc[4] + s4, b1.x), 0.0f);
        r1.y = fmaxf(fmaf(dv, acc[5] + s5, b1.y), 0.0f);
        r1.z = fmaxf(fmaf(dv, acc[6] + s6, b1.z), 0.0f);
        r1.w = fmaxf(fmaf(dv, acc[7] + s7, b1.w), 0.0f);
        *(float4*)&out[(size_t)n * F_OUT + h * 8] = r0;
        *(float4*)&out[(size_t)n * F_OUT + h * 8 + 4] = r1;
    }
}

extern "C" void kernel_launch(void* const* d_in, const int* in_sizes, int n_in,
                              void* d_out, int out_size, void* d_ws, size_t ws_size,
                              hipStream_t stream) {
    const float* x = (const float*)d_in[0];
    const int* adj = (const int*)d_in[1];
    const float* W = (const float*)d_in[2];
    const float* b = (const float*)d_in[3];
    float* out = (float*)d_out;

    int N = in_sizes[0] / F_IN;  // 50000 (u32/u16 packing assumes N <= 65536)
    int E = in_sizes[1] / 2;     // 800000
    int nbins = (N + BINW - 1) >> BSH;             // 391 (<= NBINS_CAP)
    const int avg = (E + nbins - 1) / nbins;       // ~2047
    int maxBin = ((avg + (avg >> 2)) + 63) & ~63;  // 2560, ~11 sd headroom

    // ws: dinv(N) | cursor(nbins*64B, padded)+bar(4) | rowOff(N+1) |
    //     csr(E u16) | staging(nbins*maxBin u32) | g16(N*32 u32)
    char* ws = (char*)d_ws;
    size_t segDinv = (((size_t)N * 4) + 255) & ~(size_t)255;
    size_t segCur = (((size_t)nbins * CSTRIDE * 4 + 64) + 255) & ~(size_t)255;
    size_t segRow = (((size_t)(N + 1) * 4) + 255) & ~(size_t)255;
    size_t segCsr = (((size_t)E * 2) + 255) & ~(size_t)255;
    size_t segStg = (((size_t)nbins * maxBin * 4) + 255) & ~(size_t)255;
    float* dinv = (float*)ws;
    int* cursor = (int*)(ws + segDinv);
    int* bar = cursor + nbins * CSTRIDE;  // inside zeroed cursor segment
    int* rowOff = (int*)(ws + segDinv + segCur);
    unsigned short* csr = (unsigned short*)(ws + segDinv + segCur + segRow);
    unsigned* staging = (unsigned*)(ws + segDinv + segCur + segRow + segCsr);
    unsigned* g16 = (unsigned*)(ws + segDinv + segCur + segRow + segCsr + segStg);

    hipMemsetAsync(cursor, 0, segCur, stream);  // zeroes cursors + barriers

    // Grid size: guaranteed co-residency (cached). Every phase is
    // grid-stride so any grid <= capacity is correct.
    static int s_grid = 0;
    if (s_grid == 0) {
        int occ = 0, dev = 0, cu = 0;
        hipOccupancyMaxActiveBlocksPerMultiprocessor(&occ, gcn_fused, 512, 0);
        hipGetDevice(&dev);
        hipDeviceGetAttribute(&cu, hipDeviceAttributeMultiprocessorCount, dev);
        if (occ < 1) occ = 1;
        if (cu < 1) cu = 256;
        long g = (long)occ * cu;
        s_grid = (int)(g < nbins ? g : nbins);  // 391 covers every phase width
    }

    gcn_fused<<<s_grid, 512, 0, stream>>>(x, adj, W, dinv, cursor, bar, rowOff,
                                          csr, staging, g16, N, E, nbins, maxBin);
    gather_epilogue<<<(N + 3) / 4, 256, 0, stream>>>(csr, rowOff, dinv, g16, b, out, N);
}

// Round 4
// 148.638 us; speedup vs baseline: 1.8257x; 1.5324x over previous
//
#include <hip/hip_runtime.h>

#define F_IN 256
#define F_OUT 64
#define BSH 7             // bin width 128 nodes
#define BINW 128
#define NBINS_CAP 512     // LDS histogram capacity in bin_count (N <= 65536)
#define BATCH 4096        // edges per block in bin_count (16 per thread, R13)
#define CSTRIDE 16        // cursor padded to one 64B line per bin

typedef __attribute__((ext_vector_type(8))) short short8;
typedef __attribute__((ext_vector_type(4))) float f32x4;

// ---------------------------------------------------------------------------
// bf16 helpers. f2bf_rne: manual RNE (scalar/cold paths). pack via HW
// v_cvt_pk_bf16_f32 (RNE, 2 floats/instr) on hot paths — R13: K3 was
// pack-VALU-bound (~36 VALU ops per 8 values with manual RNE; now 4).
// ---------------------------------------------------------------------------
__device__ inline unsigned short f2bf_rne(float f) {
    unsigned u = __float_as_uint(f);
    return (unsigned short)((u + 0x7fffu + ((u >> 16) & 1u)) >> 16);
}
__device__ inline float bf_lo(unsigned u) { return __uint_as_float(u << 16); }
__device__ inline float bf_hi(unsigned u) { return __uint_as_float(u & 0xFFFF0000u); }
__device__ inline unsigned cvt_pk_bf16(float lo, float hi) {
    unsigned r;
    asm("v_cvt_pk_bf16_f32 %0, %1, %2" : "=v"(r) : "v"(lo), "v"(hi));
    return r;
}
// Pack 8 floats -> 8 RNE bf16 (A-fragment order: [k0,k1][k2,k3][k4,k5][k6,k7]).
__device__ inline short8 pack_cvt(float4 a, float4 b) {
    union { unsigned u[4]; short8 s; } r;
    r.u[0] = cvt_pk_bf16(a.x, a.y);
    r.u[1] = cvt_pk_bf16(a.z, a.w);
    r.u[2] = cvt_pk_bf16(b.x, b.y);
    r.u[3] = cvt_pk_bf16(b.z, b.w);
    return r.s;
}

// ---------------------------------------------------------------------------
// K1: bin edges by dst>>BSH into per-bin staging (packed u32: src | dstLow<<16,
// valid for N <= 65536). Cursor padded to one 64B line per bin (R9 lesson).
// R13: 16 edges/thread -> 196 blocks -> per-cursor-line atomic queue depth
// 196 instead of 782 (the contended atomic-with-return round was the
// dominant serial chain; scatter/hist phases are block-count-insensitive).
// ---------------------------------------------------------------------------
__global__ __launch_bounds__(256) void bin_count(const int* __restrict__ adj,
                                                 unsigned* __restrict__ staging,
                                                 int* __restrict__ cursor,
                                                 int E, int nbins, int maxBin) {
    __shared__ int cnt[NBINS_CAP];
    __shared__ int base[NBINS_CAP];
    const int tid = threadIdx.x;
    for (int i = tid; i < NBINS_CAP; i += 256) cnt[i] = 0;
    __syncthreads();

    const int e0 = blockIdx.x * BATCH + tid * 16;
    int S[16], D[16], sl[16];
    int nv = 0;
    if (e0 + 16 <= E) {
#pragma unroll
        for (int k = 0; k < 4; k++) {
            *(int4*)&S[k * 4] = *(const int4*)&adj[e0 + k * 4];
            *(int4*)&D[k * 4] = *(const int4*)&adj[E + e0 + k * 4];
        }
        nv = 16;
    } else if (e0 < E) {
        for (int k = 0; k < 16 && e0 + k < E; k++) {
            S[k] = adj[e0 + k];
            D[k] = adj[E + e0 + k];
            nv++;
        }
    }
#pragma unroll
    for (int j = 0; j < 16; j++) {
        if (j < nv) sl[j] = atomicAdd(&cnt[D[j] >> BSH], 1);
    }
    __syncthreads();
    for (int i = tid; i < nbins; i += 256) {
        int cv = cnt[i];
        base[i] = cv ? atomicAdd(&cursor[i * CSTRIDE], cv) : 0;
    }
    __syncthreads();
#pragma unroll
    for (int j = 0; j < 16; j++) {
        if (j < nv) {
            int b = D[j] >> BSH;
            int pos = base[b] + sl[j];
            if (pos < maxBin)
                staging[(size_t)b * maxBin + pos] =
                    (unsigned)S[j] | ((unsigned)(D[j] & (BINW - 1)) << 16);
        }
    }
}

// ---------------------------------------------------------------------------
// K2: fused scan+scatter, one block per 128-node bin (391-way parallel).
// Wave 0 reduces prior-bin counts for the global base; LDS histogram of
// staged dstLows; 2-wave exclusive scan; write rowOff AND dinv=rsqrt(deg+1);
// scatter srcs into csr (ushort) via LDS cursors (one ~4KB window per block).
// ---------------------------------------------------------------------------
__global__ __launch_bounds__(256) void build_csr(const unsigned* __restrict__ staging,
                                                 const int* __restrict__ cursor,
                                                 int* __restrict__ rowOff,
                                                 float* __restrict__ dinv,
                                                 unsigned short* __restrict__ csr,
                                                 int N, int maxBin, int nbins) {
    __shared__ int degL[BINW];
    __shared__ int cur[BINW];
    __shared__ int wsum[2];
    __shared__ int baseSh;
    const int b = blockIdx.x;
    const int tid = threadIdx.x;
    const int nb0 = b << BSH;
    const int segCnt = min(cursor[b * CSTRIDE], maxBin);
    const unsigned* seg = staging + (size_t)b * maxBin;

    if (tid < 64) {  // base = staged edges in bins before this one
        int v = 0;
        for (int j = tid; j < b; j += 64) v += min(cursor[j * CSTRIDE], maxBin);
        for (int d = 1; d < 64; d <<= 1) v += __shfl_xor(v, d, 64);
        if (tid == 0) baseSh = v;
    }
    if (tid < BINW) degL[tid] = 0;
    __syncthreads();
    const int base = baseSh;

    for (int i = tid; i < segCnt; i += 256) atomicAdd(&degL[seg[i] >> 16], 1);
    __syncthreads();

    int incl = 0, v = 0;
    if (tid < BINW) {  // 2-wave exclusive scan of degL[128]
        const int lane = tid & 63;
        v = degL[tid];
        incl = v;
        for (int d = 1; d < 64; d <<= 1) {
            int t = __shfl_up(incl, d, 64);
            if (lane >= d) incl += t;
        }
        if (lane == 63) wsum[tid >> 6] = incl;
    }
    __syncthreads();
    if (tid < BINW) {
        int ex = incl - v + ((tid >= 64) ? wsum[0] : 0);
        cur[tid] = ex;
        int node = nb0 + tid;
        if (node < N) {
            rowOff[node] = base + ex;
            dinv[node] = rsqrtf((float)v + 1.0f);
        }
    }
    if (b == nbins - 1 && tid == 0) rowOff[N] = base + segCnt;
    __syncthreads();

    for (int i = tid; i < segCnt; i += 256) {
        unsigned e = seg[i];
        int pos = atomicAdd(&cur[e >> 16], 1);
        csr[base + pos] = (unsigned short)(e & 0xFFFFu);
    }
}

// ---------------------------------------------------------------------------
// K3: g(bf16) = dinv[n] * (x @ W) via bf16 MFMA, x as single RNE bf16.
// R13: pack via v_cvt_pk_bf16_f32 (HW RNE == manual RNE bits) — was the
// dominant VALU cost (R10 diagnosis). 512-thread blocks, 16 nodes/wave,
// W in B-fragment-major LDS.
// ---------------------------------------------------------------------------
__global__ __launch_bounds__(512, 4) void gemm_mfma(const float* __restrict__ x,
                                                    const float* __restrict__ W,
                                                    const float* __restrict__ dinv,
                                                    unsigned* __restrict__ gu, int N) {
    __shared__ unsigned Wf[32 * 64 * 4];  // 32 KB: [kchunk][n][4 x u32(bf16x2)]
    for (int p = threadIdx.x; p < (F_IN / 2) * F_OUT; p += 512) {
        int kp = p >> 6;
        int n = p & 63;
        int k = kp * 2;
        Wf[((k >> 3) * 64 + n) * 4 + ((k & 7) >> 1)] =
            cvt_pk_bf16(W[k * F_OUT + n], W[(k + 1) * F_OUT + n]);
    }
    __syncthreads();

    const int wave = threadIdx.x >> 6;
    const int lane = threadIdx.x & 63;
    const int q = lane >> 4;
    const int c = lane & 15;
    const int n0 = blockIdx.x * 128 + wave * 16;
    const int r = min(n0 + c, N - 1);
    const float* p0 = x + (size_t)r * F_IN + q * 8;

    f32x4 acc[4] = {};
#pragma unroll
    for (int s = 0; s < 8; s++) {
        float4 a0 = *(const float4*)(p0 + s * 32);
        float4 a1 = *(const float4*)(p0 + s * 32 + 4);
        short8 ah = pack_cvt(a0, a1);
#pragma unroll
        for (int t = 0; t < 4; t++) {
            short8 bh = *(const short8*)&Wf[((s * 4 + q) * 64 + t * 16 + c) * 4];
            acc[t] = __builtin_amdgcn_mfma_f32_16x16x32_bf16(ah, bh, acc[t], 0, 0, 0);
        }
    }

    // D layout: col = t*16 + c (feature), row = q*4 + rr (node). Pack col
    // pairs via shfl_xor(1), store bf16x2.
#pragma unroll
    for (int rr = 0; rr < 4; rr++) {
        int node = n0 + q * 4 + rr;
        float dv = dinv[min(node, N - 1)];
#pragma unroll
        for (int t = 0; t < 4; t++) {
            float v = acc[t][rr] * dv;
            float o = __shfl_xor(v, 1, 64);
            if (node < N && !(lane & 1)) {
                gu[(size_t)node * 32 + t * 8 + (c >> 1)] = cvt_pk_bf16(v, o);
            }
        }
    }
}

// ---------------------------------------------------------------------------
// K4: gather + fused epilogue. Wave = node; 8 groups of 8 lanes, each lane
// loads uint4 (16B, cols 8h..8h+7) -> one 128B request per group per edge.
// 2-deep unroll: at avg deg 16 each group runs exactly one full iteration
// (2 loads in flight, 16/wave). Cross-group reduce via shfl_xor 8/16/32.
// ---------------------------------------------------------------------------
__global__ __launch_bounds__(256) void gather_epilogue(const unsigned short* __restrict__ csr,
                                                       const int* __restrict__ rowOff,
                                                       const float* __restrict__ dinv,
                                                       const unsigned* __restrict__ g32,
                                                       const float* __restrict__ bias,
                                                       float* __restrict__ out, int N) {
    int n = blockIdx.x * 4 + (threadIdx.x >> 6);
    if (n >= N) return;
    const int lane = threadIdx.x & 63;
    const int grp = lane >> 3;
    const int h = lane & 7;
    const int start = rowOff[n], end = rowOff[n + 1];
    const uint4* g4 = (const uint4*)g32;

    float a0[8] = {}, a1[8] = {};
    int i = start + grp;
    for (; i + 8 < end; i += 16) {
        int s0 = csr[i], s1 = csr[i + 8];
        uint4 u0 = g4[(size_t)s0 * 8 + h];
        uint4 u1 = g4[(size_t)s1 * 8 + h];
        a0[0] += bf_lo(u0.x); a0[1] += bf_hi(u0.x);
        a0[2] += bf_lo(u0.y); a0[3] += bf_hi(u0.y);
        a0[4] += bf_lo(u0.z); a0[5] += bf_hi(u0.z);
        a0[6] += bf_lo(u0.w); a0[7] += bf_hi(u0.w);
        a1[0] += bf_lo(u1.x); a1[1] += bf_hi(u1.x);
        a1[2] += bf_lo(u1.y); a1[3] += bf_hi(u1.y);
        a1[4] += bf_lo(u1.z); a1[5] += bf_hi(u1.z);
        a1[6] += bf_lo(u1.w); a1[7] += bf_hi(u1.w);
    }
    if (i < end) {
        int s0 = csr[i];
        uint4 u0 = g4[(size_t)s0 * 8 + h];
        a0[0] += bf_lo(u0.x); a0[1] += bf_hi(u0.x);
        a0[2] += bf_lo(u0.y); a0[3] += bf_hi(u0.y);
        a0[4] += bf_lo(u0.z); a0[5] += bf_hi(u0.z);
        a0[6] += bf_lo(u0.w); a0[7] += bf_hi(u0.w);
    }
    float acc[8];
#pragma unroll
    for (int k = 0; k < 8; k++) acc[k] = a0[k] + a1[k];
#pragma unroll
    for (int m = 8; m < 64; m <<= 1) {
#pragma unroll
        for (int k = 0; k < 8; k++) acc[k] += __shfl_xor(acc[k], m, 64);
    }
    if (grp == 0) {
        uint4 us = g4[(size_t)n * 8 + h];  // self loop
        float dv = dinv[n];
        float s0 = bf_lo(us.x), s1 = bf_hi(us.x), s2 = bf_lo(us.y), s3 = bf_hi(us.y);
        float s4 = bf_lo(us.z), s5 = bf_hi(us.z), s6 = bf_lo(us.w), s7 = bf_hi(us.w);
        float4 b0 = *(const float4*)&bias[h * 8];
        float4 b1 = *(const float4*)&bias[h * 8 + 4];
        float4 r0, r1;
        r0.x = fmaxf(fmaf(dv, acc[0] + s0, b0.x), 0.0f);
        r0.y = fmaxf(fmaf(dv, acc[1] + s1, b0.y), 0.0f);
        r0.z = fmaxf(fmaf(dv, acc[2] + s2, b0.z), 0.0f);
        r0.w = fmaxf(fmaf(dv, acc[3] + s3, b0.w), 0.0f);
        r1.x = fmaxf(fmaf(dv, acc[4] + s4, b1.x), 0.0f);
        r1.y = fmaxf(fmaf(dv, acc[5] + s5, b1.y), 0.0f);
        r1.z = fmaxf(fmaf(dv, acc[6] + s6, b1.z), 0.0f);
        r1.w = fmaxf(fmaf(dv, acc[7] + s7, b1.w), 0.0f);
        *(float4*)&out[(size_t)n * F_OUT + h * 8] = r0;
        *(float4*)&out[(size_t)n * F_OUT + h * 8 + 4] = r1;
    }
}

extern "C" void kernel_launch(void* const* d_in, const int* in_sizes, int n_in,
                              void* d_out, int out_size, void* d_ws, size_t ws_size,
                              hipStream_t stream) {
    const float* x = (const float*)d_in[0];
    const int* adj = (const int*)d_in[1];
    const float* W = (const float*)d_in[2];
    const float* b = (const float*)d_in[3];
    float* out = (float*)d_out;

    const int N = in_sizes[0] / F_IN;  // 50000 (u32/u16 packing assumes N <= 65536)
    const int E = in_sizes[1] / 2;     // 800000
    const int nbins = (N + BINW - 1) >> BSH;             // 391 (<= NBINS_CAP)
    const int avg = (E + nbins - 1) / nbins;             // ~2047
    const int maxBin = ((avg + (avg >> 2)) + 63) & ~63;  // 2560, ~11 sd headroom

    // ws: dinv(N) | cursor(nbins*64B, padded) | rowOff(N+1) | csr(E u16) |
    //     staging(nbins*maxBin u32) | g16(N*32 u32)
    char* ws = (char*)d_ws;
    size_t segDinv = (((size_t)N * 4) + 255) & ~(size_t)255;
    size_t segCur = (((size_t)nbins * CSTRIDE * 4) + 255) & ~(size_t)255;
    size_t segRow = (((size_t)(N + 1) * 4) + 255) & ~(size_t)255;
    size_t segCsr = (((size_t)E * 2) + 255) & ~(size_t)255;
    size_t segStg = (((size_t)nbins * maxBin * 4) + 255) & ~(size_t)255;
    float* dinv = (float*)ws;
    int* cursor = (int*)(ws + segDinv);
    int* rowOff = (int*)(ws + segDinv + segCur);
    unsigned short* csr = (unsigned short*)(ws + segDinv + segCur + segRow);
    unsigned* staging = (unsigned*)(ws + segDinv + segCur + segRow + segCsr);
    unsigned* g16 = (unsigned*)(ws + segDinv + segCur + segRow + segCsr + segStg);

    hipMemsetAsync(cursor, 0, segCur, stream);

    bin_count<<<(E + BATCH - 1) / BATCH, 256, 0, stream>>>(adj, staging, cursor,
                                                           E, nbins, maxBin);
    build_csr<<<nbins, 256, 0, stream>>>(staging, cursor, rowOff, dinv, csr,
                                         N, maxBin, nbins);
    gemm_mfma<<<(N + 127) / 128, 512, 0, stream>>>(x, W, dinv, g16, N);
    gather_epilogue<<<(N + 3) / 4, 256, 0, stream>>>(csr, rowOff, dinv, g16, b, out, N);
}